// Round 8
// baseline (150.836 us; speedup 1.0000x reference)
//
#include <hip/hip_runtime.h>
#include <math.h>

// MoE router on MFMA: logits = (x @ W1^T + b1) @ W2^T + b2; softmax; top-2; masks.
// N=32768, D=1024, D_H=512, E=8, K=2.
//
// Split-fp16: x = xh+xl, W1 = wh+wl; h = xh*wh + xl*wh + xh*wl (3 MFMA passes,
// fp32 acc). W1 pre-split/pre-packed into 32x32x16 fragment order in d_ws (r4).
//
// Round-8: 1024 threads / 16 waves, wave tile 64x64 (acc = 4 x f32x16 = 64
// regs) -> 4 waves/SIMD at the 128-reg cap. r6/r7 showed the loop is
// latency-bound at 2 waves/SIMD (MfmaUtil pinned at 24%); doubling resident
// waves doubles latency cover. MFMA order interleaved across accs (same-acc
// 4 apart). B register-direct from L2 per sub-tile; A LDS dbuf; 1 barrier/iter.

#define N_TOK 32768
#define D_IN  1024
#define D_H   512
#define N_EXP 8

#define BM      128
#define THREADS 1024
#define NKT2    32            // 32-wide k-tiles
#define WSLOTS  (64 * 1024)   // W1 frag slots per hi/lo plane (16-wide tiles)

typedef _Float16 f16;
typedef __attribute__((ext_vector_type(4)))  _Float16 f16x4;
typedef __attribute__((ext_vector_type(8)))  _Float16 f16x8;
typedef __attribute__((ext_vector_type(16))) float    f32x16;

#define MFMA(a, b, c) __builtin_amdgcn_mfma_f32_32x32x16_f16((a), (b), (c), 0, 0, 0)

// ---- pre-kernel: split W1 into hi/lo f16 fragments in ws (verified r4-r7) ----
__global__ void split_w1(const float* __restrict__ W1,
                         f16* __restrict__ wsH, f16* __restrict__ wsL) {
    const int s = blockIdx.x * 256 + threadIdx.x;   // 0..65535
    const int kt  = s >> 10;
    const int ctg = (s >> 6) & 15;
    const int l   = s & 63;
    const int n   = ctg * 32 + (l & 31);
    const int k   = kt * 16 + (l >> 5) * 8;
    const float* src = &W1[(size_t)n * D_IN + k];
    float4 a0 = *(const float4*)src;
    float4 a1 = *(const float4*)(src + 4);
    f16x8 hi, lo;
#pragma unroll
    for (int j = 0; j < 4; ++j) {
        float v0 = ((const float*)&a0)[j];
        float v1 = ((const float*)&a1)[j];
        _Float16 h0 = (_Float16)v0, h1 = (_Float16)v1;
        hi[j] = h0;     hi[j + 4] = h1;
        lo[j] = (_Float16)(v0 - (float)h0);
        lo[j + 4] = (_Float16)(v1 - (float)h1);
    }
    *(f16x8*)&wsH[(size_t)s * 8] = hi;
    *(f16x8*)&wsL[(size_t)s * 8] = lo;
}

// ---- main kernel ----
__global__ __launch_bounds__(THREADS, 1)   // 1 block/CU: 16 waves -> 4/SIMD -> 128-reg cap
void moe_router_mfma(const float* __restrict__ x,
                     const f16* __restrict__ wH,
                     const f16* __restrict__ wL,
                     const float* __restrict__ b1,
                     const float* __restrict__ W2,
                     const float* __restrict__ b2,
                     float* __restrict__ out)
{
    // A frag dbuf (2 buf x 2 plane x 4096 f16 = 32 KB) UNION epilogue h_s
    // ([32][512] f32 = 64 KB). A dead in epilogue; barrier-separated.
    __shared__ __align__(16) unsigned char SMEM[65536];
    __shared__ __align__(16) float W2s[N_EXP * D_H];     // 16 KB
    __shared__ __align__(16) float b1s[D_H];             // 2 KB
    __shared__ float b2s[N_EXP];

    f16*   AS  = (f16*)SMEM;      // [(buf*2+plane)*4096 + sub*2048 + frag*8]
    float* h_s = (float*)SMEM;    // epilogue only

    const int t    = threadIdx.x;
    const int w    = t >> 6;
    const int lane = t & 63;
    const int rg   = w >> 3;      // row-group 0..1 (64 rows each)
    const int cg   = w & 7;       // col-group 0..7 (64 cols each)
    const int m0   = blockIdx.x * BM;

    // wave tile 64x64: acc[rt][ct], rt,ct in {0,1}
    f32x16 a0c0 = {}, a0c1 = {}, a1c0 = {}, a1c1 = {};

    // A staging geometry: 1024 threads stage 128 rows x 32 k per iter
    // (one float4 each). sub = t>>9 (16-wide half), frag fA, quarter qA.
    const int subA = t >> 9;
    const int t9   = t & 511;
    const int fA   = t9 >> 1;           // 0..255: rtg = fA>>6, slot-lane = fA&63
    const int qA   = t9 & 1;
    const int lA   = fA & 63;
    const int rowA = (fA >> 6) * 32 + (lA & 31);
    const int kA   = ((lA >> 5) & 1) * 8 + qA * 4;
    const float* xsrc = x + (size_t)(m0 + rowA) * D_IN + subA * 16 + kA;
    const int aDst = subA * 2048 + fA * 8 + qA * 4;   // f16 idx within a plane

    // B frag offsets for this wave's two col-tiles (within a 16-ktile plane)
    const size_t bOff0 = (size_t)(2 * cg + 0) * 512 + (size_t)lane * 8;
    const size_t bOff1 = (size_t)(2 * cg + 1) * 512 + (size_t)lane * 8;

    auto stageAwrite = [&](const float4& xv, int buf) {
        f16x4 hi, lo;
        float v[4] = {xv.x, xv.y, xv.z, xv.w};
#pragma unroll
        for (int j = 0; j < 4; ++j) {
            _Float16 h = (_Float16)v[j];
            hi[j] = h;
            lo[j] = (_Float16)(v[j] - (float)h);
        }
        *(f16x4*)&AS[(buf * 2 + 0) * 4096 + aDst] = hi;
        *(f16x4*)&AS[(buf * 2 + 1) * 4096 + aDst] = lo;
    };

    // ---- prologue: stage A ktile 0 ----
    stageAwrite(*(const float4*)xsrc, 0);
    __syncthreads();

    for (int ktt = 0; ktt < NKT2; ++ktt) {
        const int cur = ktt & 1;
        const int nxt = cur ^ 1;

        float4 xn = {0.f, 0.f, 0.f, 0.f};
        if (ktt + 1 < NKT2)
            xn = *(const float4*)(xsrc + (size_t)(ktt + 1) * 32);

        const f16* ah = &AS[(cur * 2 + 0) * 4096];
        const f16* al = &AS[(cur * 2 + 1) * 4096];

#pragma unroll
        for (int sub = 0; sub < 2; ++sub) {
            const size_t kb = (size_t)(2 * ktt + sub) * 8192;
            // B: register-direct from L2 (wave-private cols)
            f16x8 Bh0 = *(const f16x8*)(wH + kb + bOff0);
            f16x8 Bh1 = *(const f16x8*)(wH + kb + bOff1);
            f16x8 Bl0 = *(const f16x8*)(wL + kb + bOff0);
            f16x8 Bl1 = *(const f16x8*)(wL + kb + bOff1);
            // A frags for this wave's two row-tiles
            const int sb = sub * 2048;
            f16x8 ah0 = *(const f16x8*)&ah[sb + ((rg * 2 + 0) * 64 + lane) * 8];
            f16x8 al0 = *(const f16x8*)&al[sb + ((rg * 2 + 0) * 64 + lane) * 8];
            f16x8 ah1 = *(const f16x8*)&ah[sb + ((rg * 2 + 1) * 64 + lane) * 8];
            f16x8 al1 = *(const f16x8*)&al[sb + ((rg * 2 + 1) * 64 + lane) * 8];

            __builtin_amdgcn_s_setprio(1);
            // pass 1: xh*wh  (interleaved across accs: same-acc 4 apart)
            a0c0 = MFMA(ah0, Bh0, a0c0);
            a1c0 = MFMA(ah1, Bh0, a1c0);
            a0c1 = MFMA(ah0, Bh1, a0c1);
            a1c1 = MFMA(ah1, Bh1, a1c1);
            // pass 2: xl*wh
            a0c0 = MFMA(al0, Bh0, a0c0);
            a1c0 = MFMA(al1, Bh0, a1c0);
            a0c1 = MFMA(al0, Bh1, a0c1);
            a1c1 = MFMA(al1, Bh1, a1c1);
            // pass 3: xh*wl
            a0c0 = MFMA(ah0, Bl0, a0c0);
            a1c0 = MFMA(ah1, Bl0, a1c0);
            a0c1 = MFMA(ah0, Bl1, a0c1);
            a1c1 = MFMA(ah1, Bl1, a1c1);
            __builtin_amdgcn_s_setprio(0);
        }

        // stage A for next iter (other buffer; ordered before the barrier)
        if (ktt + 1 < NKT2) stageAwrite(xn, nxt);
        __syncthreads();   // single barrier per 32-wide ktile
    }

    // ---- epilogue (router tail verified r4-r7) ----
    ((float4*)W2s)[t] = ((const float4*)W2)[t];          // 1024 x 16B = 16 KB
    if (t < D_H / 4) ((float4*)b1s)[t] = ((const float4*)b1)[t];
    if (t < N_EXP) b2s[t] = b2[t];
    __syncthreads();

    const int n0  = cg * 64 + (lane & 31);   // C/D layout: col = lane&31
    const int n1  = n0 + 32;
    const float bn0 = b1s[n0];
    const float bn1 = b1s[n1];

    float* out_logits = out;
    float* out_w      = out + (size_t)N_TOK * N_EXP;
    float* out_i      = out_w + (size_t)N_TOK * 2;
    float* out_m      = out_i + (size_t)N_TOK * 2;

    auto reduce_rows = [&](int g) {
#pragma unroll
        for (int rr2 = 0; rr2 < 2; ++rr2) {
            const int rl   = w * 2 + rr2;            // 16 waves x 2 = 32 rows
            const int grow = m0 + g * 32 + rl;
            float4 ha = *(const float4*)&h_s[rl * 512 + lane * 4];
            float4 hb = *(const float4*)&h_s[rl * 512 + 256 + lane * 4];
            float v1 = -3.4e38f, v2 = -3.4e38f;
            int   i1 = 0, i2 = 0;
            float pls[8];
#pragma unroll
            for (int e = 0; e < N_EXP; ++e) {
                float4 wa = *(const float4*)&W2s[e * D_H + lane * 4];
                float4 wb = *(const float4*)&W2s[e * D_H + 256 + lane * 4];
                float s = ha.x * wa.x;
                s = fmaf(ha.y, wa.y, s);
                s = fmaf(ha.z, wa.z, s);
                s = fmaf(ha.w, wa.w, s);
                s = fmaf(hb.x, wb.x, s);
                s = fmaf(hb.y, wb.y, s);
                s = fmaf(hb.z, wb.z, s);
                s = fmaf(hb.w, wb.w, s);
#pragma unroll
                for (int off = 1; off < 64; off <<= 1)
                    s += __shfl_xor(s, off);
                s += b2s[e];
                pls[e] = s;
                if (s > v1)      { v2 = v1; i2 = i1; v1 = s; i1 = e; }
                else if (s > v2) { v2 = s;  i2 = e; }
            }
            const float rr   = expf(v2 - v1);
            const float wden = 1.f / (1.f + rr);
            if (lane == 0) {
                float4 lo4 = {pls[0], pls[1], pls[2], pls[3]};
                float4 hi4 = {pls[4], pls[5], pls[6], pls[7]};
                *(float4*)&out_logits[(size_t)grow * N_EXP]     = lo4;
                *(float4*)&out_logits[(size_t)grow * N_EXP + 4] = hi4;
                float2 wv = {wden, rr * wden};
                *(float2*)&out_w[(size_t)grow * 2] = wv;
                float2 iv = {(float)i1, (float)i2};
                *(float2*)&out_i[(size_t)grow * 2] = iv;
            }
            if (lane < 16) {
                const int e   = lane >> 1;
                const int kk  = lane & 1;
                const int sel = kk ? i2 : i1;
                out_m[((size_t)(e * 2 + kk)) * N_TOK + grow] = (sel == e) ? 1.0f : 0.0f;
            }
        }
    };

    // 4 groups of 32 rows. Group g is produced by waves with rg == g>>1 from
    // their local acc (g&1). C/D row map (verified): (rr&3)+8*(rr>>2)+4*(lane>>5)
#define DO_GROUP(RGSEL, AC0, AC1, G) do {                                      \
        if (rg == (RGSEL)) {                                                   \
            _Pragma("unroll")                                                  \
            for (int rr = 0; rr < 16; ++rr) {                                  \
                const int rl = (rr & 3) + 8 * (rr >> 2) + 4 * (lane >> 5);     \
                h_s[rl * 512 + n0] = AC0[rr] + bn0;                            \
                h_s[rl * 512 + n1] = AC1[rr] + bn1;                            \
            }                                                                  \
        }                                                                      \
        __syncthreads();                                                       \
        reduce_rows(G);                                                        \
        __syncthreads();                                                       \
    } while (0)

    DO_GROUP(0, a0c0, a0c1, 0);
    DO_GROUP(0, a1c0, a1c1, 1);
    DO_GROUP(1, a0c0, a0c1, 2);
    DO_GROUP(1, a1c0, a1c1, 3);
#undef DO_GROUP
}

extern "C" void kernel_launch(void* const* d_in, const int* in_sizes, int n_in,
                              void* d_out, int out_size, void* d_ws, size_t ws_size,
                              hipStream_t stream) {
    const float* x  = (const float*)d_in[0];
    const float* W1 = (const float*)d_in[1];
    const float* b1 = (const float*)d_in[2];
    const float* W2 = (const float*)d_in[3];
    const float* b2 = (const float*)d_in[4];
    float* out = (float*)d_out;

    f16* wsH = (f16*)d_ws;                       // 1 MB
    f16* wsL = wsH + (size_t)WSLOTS * 8;         // 1 MB

    split_w1<<<WSLOTS / 256, 256, 0, stream>>>(W1, wsH, wsL);
    moe_router_mfma<<<N_TOK / BM, THREADS, 0, stream>>>(x, wsH, wsL, b1, W2, b2, out);
}

// Round 9
// 147.275 us; speedup vs baseline: 1.0242x; 1.0242x over previous
//
#include <hip/hip_runtime.h>
#include <math.h>

// MoE router on MFMA: logits = (x @ W1^T + b1) @ W2^T + b2; softmax; top-2; masks.
// N=32768, D=1024, D_H=512, E=8, K=2.
//
// Split-fp16: x = xh+xl, W1 = wh+wl; h = xh*wh + xl*wh + xh*wl (3 MFMA passes,
// fp32 acc). W1 pre-split/pre-packed into 32x32x16 fragment order in d_ws (r4).
//
// Round-9: keep r8's 16-wave / 64x64-wave-tile / 4 waves-per-SIMD shape, but
// fit the ARCH-VGPR working set into the 64-reg partition (r8 spilled: the
// unrolled sub-loop hoisted both subs' B+A frags -> ~75 live > 64 arch regs;
// WRITE_SIZE 3.6->54 MB). Fix: #pragma unroll 1 on the sub-loop (no cross-sub
// hoisting) + defer the al ds_reads until pass 2. Spill tripwire: WRITE_SIZE
// must return to ~3.6 MB.

#define N_TOK 32768
#define D_IN  1024
#define D_H   512
#define N_EXP 8

#define BM      128
#define THREADS 1024
#define NKT2    32            // 32-wide k-tiles
#define WSLOTS  (64 * 1024)   // W1 frag slots per hi/lo plane (16-wide tiles)

typedef _Float16 f16;
typedef __attribute__((ext_vector_type(4)))  _Float16 f16x4;
typedef __attribute__((ext_vector_type(8)))  _Float16 f16x8;
typedef __attribute__((ext_vector_type(16))) float    f32x16;

#define MFMA(a, b, c) __builtin_amdgcn_mfma_f32_32x32x16_f16((a), (b), (c), 0, 0, 0)

// ---- pre-kernel: split W1 into hi/lo f16 fragments in ws (verified r4-r8) ----
__global__ void split_w1(const float* __restrict__ W1,
                         f16* __restrict__ wsH, f16* __restrict__ wsL) {
    const int s = blockIdx.x * 256 + threadIdx.x;   // 0..65535
    const int kt  = s >> 10;
    const int ctg = (s >> 6) & 15;
    const int l   = s & 63;
    const int n   = ctg * 32 + (l & 31);
    const int k   = kt * 16 + (l >> 5) * 8;
    const float* src = &W1[(size_t)n * D_IN + k];
    float4 a0 = *(const float4*)src;
    float4 a1 = *(const float4*)(src + 4);
    f16x8 hi, lo;
#pragma unroll
    for (int j = 0; j < 4; ++j) {
        float v0 = ((const float*)&a0)[j];
        float v1 = ((const float*)&a1)[j];
        _Float16 h0 = (_Float16)v0, h1 = (_Float16)v1;
        hi[j] = h0;     hi[j + 4] = h1;
        lo[j] = (_Float16)(v0 - (float)h0);
        lo[j + 4] = (_Float16)(v1 - (float)h1);
    }
    *(f16x8*)&wsH[(size_t)s * 8] = hi;
    *(f16x8*)&wsL[(size_t)s * 8] = lo;
}

// ---- main kernel ----
__global__ __launch_bounds__(THREADS, 1)   // 16 waves -> 4/SIMD -> 128 unified regs
void moe_router_mfma(const float* __restrict__ x,
                     const f16* __restrict__ wH,
                     const f16* __restrict__ wL,
                     const float* __restrict__ b1,
                     const float* __restrict__ W2,
                     const float* __restrict__ b2,
                     float* __restrict__ out)
{
    // A frag dbuf (2 buf x 2 plane x 4096 f16 = 32 KB) UNION epilogue h_s
    // ([32][512] f32 = 64 KB). A dead in epilogue; barrier-separated.
    __shared__ __align__(16) unsigned char SMEM[65536];
    __shared__ __align__(16) float W2s[N_EXP * D_H];     // 16 KB
    __shared__ __align__(16) float b1s[D_H];             // 2 KB
    __shared__ float b2s[N_EXP];

    f16*   AS  = (f16*)SMEM;      // [(buf*2+plane)*4096 + sub*2048 + frag*8]
    float* h_s = (float*)SMEM;    // epilogue only

    const int t    = threadIdx.x;
    const int w    = t >> 6;
    const int lane = t & 63;
    const int rg   = w >> 3;      // row-group 0..1 (64 rows each)
    const int cg   = w & 7;       // col-group 0..7 (64 cols each)
    const int m0   = blockIdx.x * BM;

    // wave tile 64x64: acc[rt][ct] -> 4 x f32x16 = 64 AGPRs
    f32x16 a0c0 = {}, a0c1 = {}, a1c0 = {}, a1c1 = {};

    // A staging geometry (verified r8): 1024 threads stage 128 rows x 32 k.
    const int subA = t >> 9;
    const int t9   = t & 511;
    const int fA   = t9 >> 1;
    const int qA   = t9 & 1;
    const int lA   = fA & 63;
    const int rowA = (fA >> 6) * 32 + (lA & 31);
    const int kA   = ((lA >> 5) & 1) * 8 + qA * 4;
    const float* xsrc = x + (size_t)(m0 + rowA) * D_IN + subA * 16 + kA;
    const int aDst = subA * 2048 + fA * 8 + qA * 4;

    // B frag offsets for this wave's two col-tiles (within a 16-ktile plane)
    const size_t bOff0 = (size_t)(2 * cg + 0) * 512 + (size_t)lane * 8;
    const size_t bOff1 = (size_t)(2 * cg + 1) * 512 + (size_t)lane * 8;

    auto stageAwrite = [&](const float4& xv, int buf) {
        f16x4 hi, lo;
        float v[4] = {xv.x, xv.y, xv.z, xv.w};
#pragma unroll
        for (int j = 0; j < 4; ++j) {
            _Float16 h = (_Float16)v[j];
            hi[j] = h;
            lo[j] = (_Float16)(v[j] - (float)h);
        }
        *(f16x4*)&AS[(buf * 2 + 0) * 4096 + aDst] = hi;
        *(f16x4*)&AS[(buf * 2 + 1) * 4096 + aDst] = lo;
    };

    // ---- prologue: stage A ktile 0 ----
    stageAwrite(*(const float4*)xsrc, 0);
    __syncthreads();

    for (int ktt = 0; ktt < NKT2; ++ktt) {
        const int cur = ktt & 1;
        const int nxt = cur ^ 1;

        float4 xn = {0.f, 0.f, 0.f, 0.f};
        if (ktt + 1 < NKT2)
            xn = *(const float4*)(xsrc + (size_t)(ktt + 1) * 32);

        const f16* ah = &AS[(cur * 2 + 0) * 4096];
        const f16* al = &AS[(cur * 2 + 1) * 4096];

        // NOT unrolled: keeps only ONE sub's B (16 VGPR) + A (<=16 VGPR) live
        // so the arch working set fits the 64-reg partition (r8 spill fix).
#pragma unroll 1
        for (int sub = 0; sub < 2; ++sub) {
            const size_t kb = (size_t)(2 * ktt + sub) * 8192;
            // B: register-direct from L2 (wave-private cols)
            f16x8 Bh0 = *(const f16x8*)(wH + kb + bOff0);
            f16x8 Bh1 = *(const f16x8*)(wH + kb + bOff1);
            f16x8 Bl0 = *(const f16x8*)(wL + kb + bOff0);
            f16x8 Bl1 = *(const f16x8*)(wL + kb + bOff1);
            const int sb = sub * 2048;
            // A hi frags only (al deferred to pass 2)
            f16x8 ah0 = *(const f16x8*)&ah[sb + ((rg * 2 + 0) * 64 + lane) * 8];
            f16x8 ah1 = *(const f16x8*)&ah[sb + ((rg * 2 + 1) * 64 + lane) * 8];

            __builtin_amdgcn_s_setprio(1);
            // pass 1: xh*wh (same-acc dep distance 4)
            a0c0 = MFMA(ah0, Bh0, a0c0);
            a1c0 = MFMA(ah1, Bh0, a1c0);
            a0c1 = MFMA(ah0, Bh1, a0c1);
            a1c1 = MFMA(ah1, Bh1, a1c1);
            __builtin_amdgcn_s_setprio(0);

            // pass 2 operands: xl frags (loaded late; 4 waves/SIMD cover latency)
            f16x8 al0 = *(const f16x8*)&al[sb + ((rg * 2 + 0) * 64 + lane) * 8];
            f16x8 al1 = *(const f16x8*)&al[sb + ((rg * 2 + 1) * 64 + lane) * 8];

            __builtin_amdgcn_s_setprio(1);
            // pass 2: xl*wh
            a0c0 = MFMA(al0, Bh0, a0c0);
            a1c0 = MFMA(al1, Bh0, a1c0);
            a0c1 = MFMA(al0, Bh1, a0c1);
            a1c1 = MFMA(al1, Bh1, a1c1);
            // pass 3: xh*wl
            a0c0 = MFMA(ah0, Bl0, a0c0);
            a1c0 = MFMA(ah1, Bl0, a1c0);
            a0c1 = MFMA(ah0, Bl1, a0c1);
            a1c1 = MFMA(ah1, Bl1, a1c1);
            __builtin_amdgcn_s_setprio(0);
        }

        // stage A for next iter (other buffer; ordered before the barrier)
        if (ktt + 1 < NKT2) stageAwrite(xn, nxt);
        __syncthreads();   // single barrier per 32-wide ktile
    }

    // ---- epilogue (router tail verified r4-r8) ----
    ((float4*)W2s)[t] = ((const float4*)W2)[t];          // 1024 x 16B = 16 KB
    if (t < D_H / 4) ((float4*)b1s)[t] = ((const float4*)b1)[t];
    if (t < N_EXP) b2s[t] = b2[t];
    __syncthreads();

    const int n0  = cg * 64 + (lane & 31);   // C/D layout: col = lane&31
    const int n1  = n0 + 32;
    const float bn0 = b1s[n0];
    const float bn1 = b1s[n1];

    float* out_logits = out;
    float* out_w      = out + (size_t)N_TOK * N_EXP;
    float* out_i      = out_w + (size_t)N_TOK * 2;
    float* out_m      = out_i + (size_t)N_TOK * 2;

    auto reduce_rows = [&](int g) {
#pragma unroll
        for (int rr2 = 0; rr2 < 2; ++rr2) {
            const int rl   = w * 2 + rr2;            // 16 waves x 2 = 32 rows
            const int grow = m0 + g * 32 + rl;
            float4 ha = *(const float4*)&h_s[rl * 512 + lane * 4];
            float4 hb = *(const float4*)&h_s[rl * 512 + 256 + lane * 4];
            float v1 = -3.4e38f, v2 = -3.4e38f;
            int   i1 = 0, i2 = 0;
            float pls[8];
#pragma unroll
            for (int e = 0; e < N_EXP; ++e) {
                float4 wa = *(const float4*)&W2s[e * D_H + lane * 4];
                float4 wb = *(const float4*)&W2s[e * D_H + 256 + lane * 4];
                float s = ha.x * wa.x;
                s = fmaf(ha.y, wa.y, s);
                s = fmaf(ha.z, wa.z, s);
                s = fmaf(ha.w, wa.w, s);
                s = fmaf(hb.x, wb.x, s);
                s = fmaf(hb.y, wb.y, s);
                s = fmaf(hb.z, wb.z, s);
                s = fmaf(hb.w, wb.w, s);
#pragma unroll
                for (int off = 1; off < 64; off <<= 1)
                    s += __shfl_xor(s, off);
                s += b2s[e];
                pls[e] = s;
                if (s > v1)      { v2 = v1; i2 = i1; v1 = s; i1 = e; }
                else if (s > v2) { v2 = s;  i2 = e; }
            }
            const float rr   = expf(v2 - v1);
            const float wden = 1.f / (1.f + rr);
            if (lane == 0) {
                float4 lo4 = {pls[0], pls[1], pls[2], pls[3]};
                float4 hi4 = {pls[4], pls[5], pls[6], pls[7]};
                *(float4*)&out_logits[(size_t)grow * N_EXP]     = lo4;
                *(float4*)&out_logits[(size_t)grow * N_EXP + 4] = hi4;
                float2 wv = {wden, rr * wden};
                *(float2*)&out_w[(size_t)grow * 2] = wv;
                float2 iv = {(float)i1, (float)i2};
                *(float2*)&out_i[(size_t)grow * 2] = iv;
            }
            if (lane < 16) {
                const int e   = lane >> 1;
                const int kk  = lane & 1;
                const int sel = kk ? i2 : i1;
                out_m[((size_t)(e * 2 + kk)) * N_TOK + grow] = (sel == e) ? 1.0f : 0.0f;
            }
        }
    };

    // 4 groups of 32 rows; group g produced by waves with rg == g>>1 from
    // local acc (g&1). C/D row map (verified): (rr&3)+8*(rr>>2)+4*(lane>>5)
#define DO_GROUP(RGSEL, AC0, AC1, G) do {                                      \
        if (rg == (RGSEL)) {                                                   \
            _Pragma("unroll")                                                  \
            for (int rr = 0; rr < 16; ++rr) {                                  \
                const int rl = (rr & 3) + 8 * (rr >> 2) + 4 * (lane >> 5);     \
                h_s[rl * 512 + n0] = AC0[rr] + bn0;                            \
                h_s[rl * 512 + n1] = AC1[rr] + bn1;                            \
            }                                                                  \
        }                                                                      \
        __syncthreads();                                                       \
        reduce_rows(G);                                                       \
        __syncthreads();                                                       \
    } while (0)

    DO_GROUP(0, a0c0, a0c1, 0);
    DO_GROUP(0, a1c0, a1c1, 1);
    DO_GROUP(1, a0c0, a0c1, 2);
    DO_GROUP(1, a1c0, a1c1, 3);
#undef DO_GROUP
}

extern "C" void kernel_launch(void* const* d_in, const int* in_sizes, int n_in,
                              void* d_out, int out_size, void* d_ws, size_t ws_size,
                              hipStream_t stream) {
    const float* x  = (const float*)d_in[0];
    const float* W1 = (const float*)d_in[1];
    const float* b1 = (const float*)d_in[2];
    const float* W2 = (const float*)d_in[3];
    const float* b2 = (const float*)d_in[4];
    float* out = (float*)d_out;

    f16* wsH = (f16*)d_ws;                       // 1 MB
    f16* wsL = wsH + (size_t)WSLOTS * 8;         // 1 MB

    split_w1<<<WSLOTS / 256, 256, 0, stream>>>(W1, wsH, wsL);
    moe_router_mfma<<<N_TOK / BM, THREADS, 0, stream>>>(x, wsH, wsL, b1, W2, b2, out);
}

// Round 10
// 144.503 us; speedup vs baseline: 1.0438x; 1.0192x over previous
//
#include <hip/hip_runtime.h>
#include <math.h>

// MoE router on MFMA: logits = (x @ W1^T + b1) @ W2^T + b2; softmax; top-2; masks.
// N=32768, D=1024, D_H=512, E=8, K=2.
//
// Split-fp16: x = xh+xl, W1 = wh+wl; h = xh*wh + xl*wh + xh*wl (3 MFMA passes,
// fp32 acc). W1 pre-split/pre-packed into 32x32x16 fragment order in d_ws (r4).
//
// Round-10: third attempt at spill-free 4 waves/SIMD (16 waves, 128-reg cap,
// 64 arch + 64 acc). r8/r9 spilled because the arch working set exceeded 64:
// size_t addressing made 64-bit VGPR address pairs per B load. Fixes:
//   1. all global loads = SGPR base + 32-bit unsigned offset (saddr form);
//   2. ct-major MFMA order per sub: only ONE col-tile's B pair (8 regs) live
//      at a time; peak live ~= A 32 + B 16 + xn 4 + offs 6 = 58 <= 64.
// Spill tripwire: WRITE_SIZE must be ~3.6 MB.

#define N_TOK 32768
#define D_IN  1024
#define D_H   512
#define N_EXP 8

#define BM      128
#define THREADS 1024
#define NKT2    32            // 32-wide k-tiles
#define WSLOTS  (64 * 1024)   // W1 frag slots per hi/lo plane (16-wide tiles)

typedef _Float16 f16;
typedef __attribute__((ext_vector_type(4)))  _Float16 f16x4;
typedef __attribute__((ext_vector_type(8)))  _Float16 f16x8;
typedef __attribute__((ext_vector_type(16))) float    f32x16;

#define MFMA(a, b, c) __builtin_amdgcn_mfma_f32_32x32x16_f16((a), (b), (c), 0, 0, 0)

// ---- pre-kernel: split W1 into hi/lo f16 fragments in ws (verified r4-r9) ----
__global__ void split_w1(const float* __restrict__ W1,
                         f16* __restrict__ wsH, f16* __restrict__ wsL) {
    const int s = blockIdx.x * 256 + threadIdx.x;   // 0..65535
    const int kt  = s >> 10;
    const int ctg = (s >> 6) & 15;
    const int l   = s & 63;
    const int n   = ctg * 32 + (l & 31);
    const int k   = kt * 16 + (l >> 5) * 8;
    const float* src = &W1[(size_t)n * D_IN + k];
    float4 a0 = *(const float4*)src;
    float4 a1 = *(const float4*)(src + 4);
    f16x8 hi, lo;
#pragma unroll
    for (int j = 0; j < 4; ++j) {
        float v0 = ((const float*)&a0)[j];
        float v1 = ((const float*)&a1)[j];
        _Float16 h0 = (_Float16)v0, h1 = (_Float16)v1;
        hi[j] = h0;     hi[j + 4] = h1;
        lo[j] = (_Float16)(v0 - (float)h0);
        lo[j + 4] = (_Float16)(v1 - (float)h1);
    }
    *(f16x8*)&wsH[(size_t)s * 8] = hi;
    *(f16x8*)&wsL[(size_t)s * 8] = lo;
}

// ---- main kernel ----
__global__ __launch_bounds__(THREADS, 1)   // 16 waves -> 4/SIMD -> 128 unified regs
void moe_router_mfma(const float* __restrict__ x,
                     const f16* __restrict__ wH,
                     const f16* __restrict__ wL,
                     const float* __restrict__ b1,
                     const float* __restrict__ W2,
                     const float* __restrict__ b2,
                     float* __restrict__ out)
{
    // A frag dbuf (2 buf x 2 plane x 4096 f16 = 32 KB) UNION epilogue h_s
    // ([32][512] f32 = 64 KB). A dead in epilogue; barrier-separated.
    __shared__ __align__(16) unsigned char SMEM[65536];
    __shared__ __align__(16) float W2s[N_EXP * D_H];     // 16 KB
    __shared__ __align__(16) float b1s[D_H];             // 2 KB
    __shared__ float b2s[N_EXP];

    f16*   AS  = (f16*)SMEM;      // [(buf*2+plane)*4096 + sub*2048 + frag*8]
    float* h_s = (float*)SMEM;    // epilogue only

    const int t    = threadIdx.x;
    const int w    = t >> 6;
    const int lane = t & 63;
    const int rg   = w >> 3;      // row-group 0..1 (64 rows each)
    const int cg   = w & 7;       // col-group 0..7 (64 cols each)
    const int m0   = blockIdx.x * BM;

    // wave tile 64x64: 4 x f32x16 = 64 AGPRs
    f32x16 a0c0 = {}, a0c1 = {}, a1c0 = {}, a1c1 = {};

    // A staging geometry (verified r8/r9): 1024 threads stage 128 rows x 32 k.
    const int subA = t >> 9;
    const int t9   = t & 511;
    const int fA   = t9 >> 1;
    const int qA   = t9 & 1;
    const int lA   = fA & 63;
    const int rowA = (fA >> 6) * 32 + (lA & 31);
    const int kA   = ((lA >> 5) & 1) * 8 + qA * 4;
    // 32-bit element offset into x (max ~33.5M < 2^31)
    const unsigned xOffBase = (unsigned)(m0 + rowA) * D_IN + subA * 16 + kA;
    const int aDst = subA * 2048 + fA * 8 + qA * 4;

    // 32-bit f16-element offsets into wH/wL planes
    const unsigned bO0 = (unsigned)(2 * cg + 0) * 512 + (unsigned)lane * 8;
    const unsigned bO1 = (unsigned)(2 * cg + 1) * 512 + (unsigned)lane * 8;
    // A-frag LDS element offsets for this wave's two row-tiles
    const int aO0 = ((rg * 2 + 0) * 64 + lane) * 8;
    const int aO1 = ((rg * 2 + 1) * 64 + lane) * 8;

    auto stageAwrite = [&](const float4& xv, int buf) {
        f16x4 hi, lo;
        float v[4] = {xv.x, xv.y, xv.z, xv.w};
#pragma unroll
        for (int j = 0; j < 4; ++j) {
            _Float16 h = (_Float16)v[j];
            hi[j] = h;
            lo[j] = (_Float16)(v[j] - (float)h);
        }
        *(f16x4*)&AS[(buf * 2 + 0) * 4096 + aDst] = hi;
        *(f16x4*)&AS[(buf * 2 + 1) * 4096 + aDst] = lo;
    };

    // ---- prologue: stage A ktile 0 ----
    stageAwrite(*(const float4*)(x + xOffBase), 0);
    __syncthreads();

    for (int ktt = 0; ktt < NKT2; ++ktt) {
        const int cur = ktt & 1;
        const int nxt = cur ^ 1;

        float4 xn = {0.f, 0.f, 0.f, 0.f};
        if (ktt + 1 < NKT2)
            xn = *(const float4*)(x + (xOffBase + (unsigned)(ktt + 1) * 32));

        const int abase = (cur * 2) * 4096;

        // NOT unrolled (cross-sub hoisting forbidden)
#pragma unroll 1
        for (int sub = 0; sub < 2; ++sub) {
            const unsigned kb = (unsigned)(2 * ktt + sub) * 8192;
            const int sb = abase + sub * 2048;

            // A frags (hi plane at sb, lo plane at sb+4096)
            f16x8 ah0 = *(const f16x8*)&AS[sb + aO0];
            f16x8 ah1 = *(const f16x8*)&AS[sb + aO1];
            f16x8 al0 = *(const f16x8*)&AS[sb + 4096 + aO0];
            f16x8 al1 = *(const f16x8*)&AS[sb + 4096 + aO1];

            // ---- col-tile 0: only Bh0/Bl0 live ----
            {
                f16x8 Bh = *(const f16x8*)(wH + (kb + bO0));
                f16x8 Bl = *(const f16x8*)(wL + (kb + bO0));
                __builtin_amdgcn_s_setprio(1);
                a0c0 = MFMA(ah0, Bh, a0c0);
                a1c0 = MFMA(ah1, Bh, a1c0);
                a0c0 = MFMA(al0, Bh, a0c0);
                a1c0 = MFMA(al1, Bh, a1c0);
                a0c0 = MFMA(ah0, Bl, a0c0);
                a1c0 = MFMA(ah1, Bl, a1c0);
                __builtin_amdgcn_s_setprio(0);
            }
            // ---- col-tile 1: only Bh1/Bl1 live ----
            {
                f16x8 Bh = *(const f16x8*)(wH + (kb + bO1));
                f16x8 Bl = *(const f16x8*)(wL + (kb + bO1));
                __builtin_amdgcn_s_setprio(1);
                a0c1 = MFMA(ah0, Bh, a0c1);
                a1c1 = MFMA(ah1, Bh, a1c1);
                a0c1 = MFMA(al0, Bh, a0c1);
                a1c1 = MFMA(al1, Bh, a1c1);
                a0c1 = MFMA(ah0, Bl, a0c1);
                a1c1 = MFMA(ah1, Bl, a1c1);
                __builtin_amdgcn_s_setprio(0);
            }
        }

        // stage A for next iter (other buffer; ordered before the barrier)
        if (ktt + 1 < NKT2) stageAwrite(xn, nxt);
        __syncthreads();   // single barrier per 32-wide ktile
    }

    // ---- epilogue (router tail verified r4-r9) ----
    ((float4*)W2s)[t] = ((const float4*)W2)[t];          // 1024 x 16B = 16 KB
    if (t < D_H / 4) ((float4*)b1s)[t] = ((const float4*)b1)[t];
    if (t < N_EXP) b2s[t] = b2[t];
    __syncthreads();

    const int n0  = cg * 64 + (lane & 31);   // C/D layout: col = lane&31
    const int n1  = n0 + 32;
    const float bn0 = b1s[n0];
    const float bn1 = b1s[n1];

    float* out_logits = out;
    float* out_w      = out + (size_t)N_TOK * N_EXP;
    float* out_i      = out_w + (size_t)N_TOK * 2;
    float* out_m      = out_i + (size_t)N_TOK * 2;

    auto reduce_rows = [&](int g) {
#pragma unroll
        for (int rr2 = 0; rr2 < 2; ++rr2) {
            const int rl   = w * 2 + rr2;            // 16 waves x 2 = 32 rows
            const int grow = m0 + g * 32 + rl;
            float4 ha = *(const float4*)&h_s[rl * 512 + lane * 4];
            float4 hb = *(const float4*)&h_s[rl * 512 + 256 + lane * 4];
            float v1 = -3.4e38f, v2 = -3.4e38f;
            int   i1 = 0, i2 = 0;
            float pls[8];
#pragma unroll
            for (int e = 0; e < N_EXP; ++e) {
                float4 wa = *(const float4*)&W2s[e * D_H + lane * 4];
                float4 wb = *(const float4*)&W2s[e * D_H + 256 + lane * 4];
                float s = ha.x * wa.x;
                s = fmaf(ha.y, wa.y, s);
                s = fmaf(ha.z, wa.z, s);
                s = fmaf(ha.w, wa.w, s);
                s = fmaf(hb.x, wb.x, s);
                s = fmaf(hb.y, wb.y, s);
                s = fmaf(hb.z, wb.z, s);
                s = fmaf(hb.w, wb.w, s);
#pragma unroll
                for (int off = 1; off < 64; off <<= 1)
                    s += __shfl_xor(s, off);
                s += b2s[e];
                pls[e] = s;
                if (s > v1)      { v2 = v1; i2 = i1; v1 = s; i1 = e; }
                else if (s > v2) { v2 = s;  i2 = e; }
            }
            const float rr   = expf(v2 - v1);
            const float wden = 1.f / (1.f + rr);
            if (lane == 0) {
                float4 lo4 = {pls[0], pls[1], pls[2], pls[3]};
                float4 hi4 = {pls[4], pls[5], pls[6], pls[7]};
                *(float4*)&out_logits[(size_t)grow * N_EXP]     = lo4;
                *(float4*)&out_logits[(size_t)grow * N_EXP + 4] = hi4;
                float2 wv = {wden, rr * wden};
                *(float2*)&out_w[(size_t)grow * 2] = wv;
                float2 iv = {(float)i1, (float)i2};
                *(float2*)&out_i[(size_t)grow * 2] = iv;
            }
            if (lane < 16) {
                const int e   = lane >> 1;
                const int kk  = lane & 1;
                const int sel = kk ? i2 : i1;
                out_m[((size_t)(e * 2 + kk)) * N_TOK + grow] = (sel == e) ? 1.0f : 0.0f;
            }
        }
    };

    // 4 groups of 32 rows; group g produced by waves with rg == g>>1 from
    // local acc (g&1). C/D row map (verified): (rr&3)+8*(rr>>2)+4*(lane>>5)
#define DO_GROUP(RGSEL, AC0, AC1, G) do {                                      \
        if (rg == (RGSEL)) {                                                   \
            _Pragma("unroll")                                                  \
            for (int rr = 0; rr < 16; ++rr) {                                  \
                const int rl = (rr & 3) + 8 * (rr >> 2) + 4 * (lane >> 5);     \
                h_s[rl * 512 + n0] = AC0[rr] + bn0;                            \
                h_s[rl * 512 + n1] = AC1[rr] + bn1;                            \
            }                                                                  \
        }                                                                      \
        __syncthreads();                                                       \
        reduce_rows(G);                                                       \
        __syncthreads();                                                       \
    } while (0)

    DO_GROUP(0, a0c0, a0c1, 0);
    DO_GROUP(0, a1c0, a1c1, 1);
    DO_GROUP(1, a0c0, a0c1, 2);
    DO_GROUP(1, a1c0, a1c1, 3);
#undef DO_GROUP
}

extern "C" void kernel_launch(void* const* d_in, const int* in_sizes, int n_in,
                              void* d_out, int out_size, void* d_ws, size_t ws_size,
                              hipStream_t stream) {
    const float* x  = (const float*)d_in[0];
    const float* W1 = (const float*)d_in[1];
    const float* b1 = (const float*)d_in[2];
    const float* W2 = (const float*)d_in[3];
    const float* b2 = (const float*)d_in[4];
    float* out = (float*)d_out;

    f16* wsH = (f16*)d_ws;                       // 1 MB
    f16* wsL = wsH + (size_t)WSLOTS * 8;         // 1 MB

    split_w1<<<WSLOTS / 256, 256, 0, stream>>>(W1, wsH, wsL);
    moe_router_mfma<<<N_TOK / BM, THREADS, 0, stream>>>(x, wsH, wsL, b1, W2, b2, out);
}

// Round 11
// 142.205 us; speedup vs baseline: 1.0607x; 1.0162x over previous
//
#include <hip/hip_runtime.h>
#include <math.h>

// MoE router on MFMA: logits = (x @ W1^T + b1) @ W2^T + b2; softmax; top-2; masks.
// N=32768, D=1024, D_H=512, E=8, K=2.
//
// Split-fp16: x = xh+xl, W1 = wh+wl; h = xh*wh + xl*wh + xh*wl (3 MFMA passes,
// fp32 acc). W1 pre-split/pre-packed into 32x32x16 fragment order in d_ws (r4).
//
// Round-11: combine the two independently-measured wins at the proven no-spill
// 2-wave/SIMD config (512 thr, BM=128, 256-reg budget):
//   - BK=32, single barrier per ktile (r7: halves per-iter fixed cost)
//   - cross-iter B register prefetch (r6: removes ~3700 cyc of in-iter L2 wait
//     from the critical path; r7 lost this and stalled)
// Liveness: next-B hi planes issued at iter top, next-B lo planes issued after
// sub0's MFMA cluster (peak live ~236 of 256). Named double-buffer via
// unroll-2 body swap (rule #20). 4-wave/128-reg quadrant abandoned (r8-r10:
// unavoidable spill, occupancy didn't move MfmaUtil).

#define N_TOK 32768
#define D_IN  1024
#define D_H   512
#define N_EXP 8

#define BM      128
#define THREADS 512
#define NKT2    32            // 32-wide k-tiles
#define WSLOTS  (64 * 1024)   // W1 frag slots per hi/lo plane (16-wide tiles)

typedef _Float16 f16;
typedef __attribute__((ext_vector_type(4)))  _Float16 f16x4;
typedef __attribute__((ext_vector_type(8)))  _Float16 f16x8;
typedef __attribute__((ext_vector_type(16))) float    f32x16;

#define MFMA(a, b, c) __builtin_amdgcn_mfma_f32_32x32x16_f16((a), (b), (c), 0, 0, 0)

// ---- pre-kernel: split W1 into hi/lo f16 fragments in ws (verified r4-r10) ----
__global__ void split_w1(const float* __restrict__ W1,
                         f16* __restrict__ wsH, f16* __restrict__ wsL) {
    const int s = blockIdx.x * 256 + threadIdx.x;   // 0..65535
    const int kt  = s >> 10;
    const int ctg = (s >> 6) & 15;
    const int l   = s & 63;
    const int n   = ctg * 32 + (l & 31);
    const int k   = kt * 16 + (l >> 5) * 8;
    const float* src = &W1[(size_t)n * D_IN + k];
    float4 a0 = *(const float4*)src;
    float4 a1 = *(const float4*)(src + 4);
    f16x8 hi, lo;
#pragma unroll
    for (int j = 0; j < 4; ++j) {
        float v0 = ((const float*)&a0)[j];
        float v1 = ((const float*)&a1)[j];
        _Float16 h0 = (_Float16)v0, h1 = (_Float16)v1;
        hi[j] = h0;     hi[j + 4] = h1;
        lo[j] = (_Float16)(v0 - (float)h0);
        lo[j + 4] = (_Float16)(v1 - (float)h1);
    }
    *(f16x8*)&wsH[(size_t)s * 8] = hi;
    *(f16x8*)&wsL[(size_t)s * 8] = lo;
}

// ---- main kernel ----
__global__ __launch_bounds__(THREADS, 1)   // 8 waves -> 2/SIMD -> 256 unified regs
void moe_router_mfma(const float* __restrict__ x,
                     const f16* __restrict__ wH,
                     const f16* __restrict__ wL,
                     const float* __restrict__ b1,
                     const float* __restrict__ W2,
                     const float* __restrict__ b2,
                     float* __restrict__ out)
{
    // A frag dbuf: [buf][plane][sub*2048 + slot*8] = 2*2*4096 f16 = 32 KB,
    // UNION epilogue h_s [32][512] f32 = 64 KB (A dead there; barrier-separated).
    __shared__ __align__(16) unsigned char SMEM[65536];
    __shared__ __align__(16) float W2s[N_EXP * D_H];     // 16 KB
    __shared__ __align__(16) float b1s[D_H];             // 2 KB
    __shared__ float b2s[N_EXP];

    f16*   AS  = (f16*)SMEM;
    float* h_s = (float*)SMEM;    // epilogue only

    const int t    = threadIdx.x;
    const int w    = t >> 6;
    const int lane = t & 63;
    const int m0   = blockIdx.x * BM;

    // 8 accumulators: row-tile rt=0..3 x col c=0..1 (wave owns cols 2w,2w+1)
    f32x16 a0c0 = {}, a0c1 = {}, a1c0 = {}, a1c1 = {};
    f32x16 a2c0 = {}, a2c1 = {}, a3c0 = {}, a3c1 = {};

    // A staging geometry (verified r4-r10): thread t -> frag fA=t>>1, qA=t&1.
    const int fA   = t >> 1;
    const int qA   = t & 1;
    const int rowA = (fA >> 6) * 32 + (fA & 31);
    const int kA   = ((fA >> 5) & 1) * 8 + qA * 4;
    const unsigned xOff = (unsigned)(m0 + rowA) * D_IN + kA;  // 32-bit offset
    const int aDst = fA * 8 + qA * 4;                         // f16 idx in sub-plane

    // B frag element offsets (within a 16-wide ktile plane of 8192 f16)
    const unsigned bO0 = (unsigned)(2 * w + 0) * 512 + (unsigned)lane * 8;
    const unsigned bO1 = bO0 + 512;
    // A-frag LDS element offsets per row-tile
    const int aO0 = ((0 * 64) + lane) * 8;
    const int aO1 = ((1 * 64) + lane) * 8;
    const int aO2 = ((2 * 64) + lane) * 8;
    const int aO3 = ((3 * 64) + lane) * 8;

    auto stageAwrite = [&](const float4& xv, int buf, int sub) {
        f16x4 hi, lo;
        float v[4] = {xv.x, xv.y, xv.z, xv.w};
#pragma unroll
        for (int j = 0; j < 4; ++j) {
            _Float16 h = (_Float16)v[j];
            hi[j] = h;
            lo[j] = (_Float16)(v[j] - (float)h);
        }
        *(f16x4*)&AS[(buf * 2 + 0) * 4096 + sub * 2048 + aDst] = hi;
        *(f16x4*)&AS[(buf * 2 + 1) * 4096 + sub * 2048 + aDst] = lo;
    };

    // ---- prologue: stage A ktile 0 + load B ktile 0 into pack A ----
    stageAwrite(*(const float4*)(x + xOff), 0, 0);
    stageAwrite(*(const float4*)(x + (xOff + 16u)), 0, 1);
    // B pack: {H,L}{sub}{col}
    f16x8 AH00 = *(const f16x8*)(wH + bO0);
    f16x8 AH01 = *(const f16x8*)(wH + bO1);
    f16x8 AH10 = *(const f16x8*)(wH + (8192u + bO0));
    f16x8 AH11 = *(const f16x8*)(wH + (8192u + bO1));
    f16x8 AL00 = *(const f16x8*)(wL + bO0);
    f16x8 AL01 = *(const f16x8*)(wL + bO1);
    f16x8 AL10 = *(const f16x8*)(wL + (8192u + bO0));
    f16x8 AL11 = *(const f16x8*)(wL + (8192u + bO1));
    f16x8 BH00, BH01, BH10, BH11, BL00, BL01, BL10, BL11;
    __syncthreads();

    // One ktile body. BUF = A LDS buffer of this ktile. Cur B pack consumed;
    // next B pack loaded here (hi at top, lo after sub0 -- liveness control).
#define BODY(BUF, KTT, CH00, CH01, CH10, CH11, CL00, CL01, CL10, CL11,         \
                       NH00, NH01, NH10, NH11, NL00, NL01, NL10, NL11)         \
    do {                                                                       \
        float4 xn0 = {0.f, 0.f, 0.f, 0.f}, xn1 = {0.f, 0.f, 0.f, 0.f};         \
        const bool more = (KTT) + 1 < NKT2;                                    \
        if (more) {                                                            \
            const unsigned nk = (unsigned)(2 * (KTT) + 2) * 8192u;             \
            NH00 = *(const f16x8*)(wH + (nk + bO0));                           \
            NH01 = *(const f16x8*)(wH + (nk + bO1));                           \
            NH10 = *(const f16x8*)(wH + (nk + 8192u + bO0));                   \
            NH11 = *(const f16x8*)(wH + (nk + 8192u + bO1));                   \
            xn0 = *(const float4*)(x + (xOff + (unsigned)((KTT) + 1) * 32u));  \
            xn1 = *(const float4*)(x + (xOff + (unsigned)((KTT) + 1) * 32u + 16u)); \
        }                                                                      \
        const int hiP = ((BUF) * 2 + 0) * 4096;                                \
        const int loP = ((BUF) * 2 + 1) * 4096;                                \
        {   /* ---- sub 0 ---- */                                              \
            f16x8 ah0 = *(const f16x8*)&AS[hiP + aO0];                         \
            f16x8 ah1 = *(const f16x8*)&AS[hiP + aO1];                         \
            f16x8 ah2 = *(const f16x8*)&AS[hiP + aO2];                         \
            f16x8 ah3 = *(const f16x8*)&AS[hiP + aO3];                         \
            f16x8 al0 = *(const f16x8*)&AS[loP + aO0];                         \
            f16x8 al1 = *(const f16x8*)&AS[loP + aO1];                         \
            f16x8 al2 = *(const f16x8*)&AS[loP + aO2];                         \
            f16x8 al3 = *(const f16x8*)&AS[loP + aO3];                         \
            __builtin_amdgcn_s_setprio(1);                                     \
            a0c0 = MFMA(ah0, CH00, a0c0);                                      \
            a1c0 = MFMA(ah1, CH00, a1c0);                                      \
            a2c0 = MFMA(ah2, CH00, a2c0);                                      \
            a3c0 = MFMA(ah3, CH00, a3c0);                                      \
            a0c1 = MFMA(ah0, CH01, a0c1);                                      \
            a1c1 = MFMA(ah1, CH01, a1c1);                                      \
            a2c1 = MFMA(ah2, CH01, a2c1);                                      \
            a3c1 = MFMA(ah3, CH01, a3c1);                                      \
            a0c0 = MFMA(al0, CH00, a0c0);                                      \
            a1c0 = MFMA(al1, CH00, a1c0);                                      \
            a2c0 = MFMA(al2, CH00, a2c0);                                      \
            a3c0 = MFMA(al3, CH00, a3c0);                                      \
            a0c1 = MFMA(al0, CH01, a0c1);                                      \
            a1c1 = MFMA(al1, CH01, a1c1);                                      \
            a2c1 = MFMA(al2, CH01, a2c1);                                      \
            a3c1 = MFMA(al3, CH01, a3c1);                                      \
            a0c0 = MFMA(ah0, CL00, a0c0);                                      \
            a1c0 = MFMA(ah1, CL00, a1c0);                                      \
            a2c0 = MFMA(ah2, CL00, a2c0);                                      \
            a3c0 = MFMA(ah3, CL00, a3c0);                                      \
            a0c1 = MFMA(ah0, CL01, a0c1);                                      \
            a1c1 = MFMA(ah1, CL01, a1c1);                                      \
            a2c1 = MFMA(ah2, CL01, a2c1);                                      \
            a3c1 = MFMA(ah3, CL01, a3c1);                                      \
            __builtin_amdgcn_s_setprio(0);                                     \
        }                                                                      \
        if (more) {   /* next-B lo planes: issued between the MFMA clusters */ \
            const unsigned nk = (unsigned)(2 * (KTT) + 2) * 8192u;             \
            NL00 = *(const f16x8*)(wL + (nk + bO0));                           \
            NL01 = *(const f16x8*)(wL + (nk + bO1));                           \
            NL10 = *(const f16x8*)(wL + (nk + 8192u + bO0));                   \
            NL11 = *(const f16x8*)(wL + (nk + 8192u + bO1));                   \
        }                                                                      \
        {   /* ---- sub 1 ---- */                                              \
            f16x8 ah0 = *(const f16x8*)&AS[hiP + 2048 + aO0];                  \
            f16x8 ah1 = *(const f16x8*)&AS[hiP + 2048 + aO1];                  \
            f16x8 ah2 = *(const f16x8*)&AS[hiP + 2048 + aO2];                  \
            f16x8 ah3 = *(const f16x8*)&AS[hiP + 2048 + aO3];                  \
            f16x8 al0 = *(const f16x8*)&AS[loP + 2048 + aO0];                  \
            f16x8 al1 = *(const f16x8*)&AS[loP + 2048 + aO1];                  \
            f16x8 al2 = *(const f16x8*)&AS[loP + 2048 + aO2];                  \
            f16x8 al3 = *(const f16x8*)&AS[loP + 2048 + aO3];                  \
            __builtin_amdgcn_s_setprio(1);                                     \
            a0c0 = MFMA(ah0, CH10, a0c0);                                      \
            a1c0 = MFMA(ah1, CH10, a1c0);                                      \
            a2c0 = MFMA(ah2, CH10, a2c0);                                      \
            a3c0 = MFMA(ah3, CH10, a3c0);                                      \
            a0c1 = MFMA(ah0, CH11, a0c1);                                      \
            a1c1 = MFMA(ah1, CH11, a1c1);                                      \
            a2c1 = MFMA(ah2, CH11, a2c1);                                      \
            a3c1 = MFMA(ah3, CH11, a3c1);                                      \
            a0c0 = MFMA(al0, CH10, a0c0);                                      \
            a1c0 = MFMA(al1, CH10, a1c0);                                      \
            a2c0 = MFMA(al2, CH10, a2c0);                                      \
            a3c0 = MFMA(al3, CH10, a3c0);                                      \
            a0c1 = MFMA(al0, CH11, a0c1);                                      \
            a1c1 = MFMA(al1, CH11, a1c1);                                      \
            a2c1 = MFMA(al2, CH11, a2c1);                                      \
            a3c1 = MFMA(al3, CH11, a3c1);                                      \
            a0c0 = MFMA(ah0, CL10, a0c0);                                      \
            a1c0 = MFMA(ah1, CL10, a1c0);                                      \
            a2c0 = MFMA(ah2, CL10, a2c0);                                      \
            a3c0 = MFMA(ah3, CL10, a3c0);                                      \
            a0c1 = MFMA(ah0, CL11, a0c1);                                      \
            a1c1 = MFMA(ah1, CL11, a1c1);                                      \
            a2c1 = MFMA(ah2, CL11, a2c1);                                      \
            a3c1 = MFMA(ah3, CL11, a3c1);                                      \
            __builtin_amdgcn_s_setprio(0);                                     \
        }                                                                      \
        if (more) {                                                            \
            stageAwrite(xn0, (BUF) ^ 1, 0);                                    \
            stageAwrite(xn1, (BUF) ^ 1, 1);                                    \
        }                                                                      \
        __syncthreads();                                                       \
    } while (0)

    for (int ktt = 0; ktt < NKT2; ktt += 2) {
        BODY(0, ktt,     AH00, AH01, AH10, AH11, AL00, AL01, AL10, AL11,
                         BH00, BH01, BH10, BH11, BL00, BL01, BL10, BL11);
        BODY(1, ktt + 1, BH00, BH01, BH10, BH11, BL00, BL01, BL10, BL11,
                         AH00, AH01, AH10, AH11, AL00, AL01, AL10, AL11);
    }
#undef BODY

    // ---- epilogue (router tail verified r4-r10) ----
    ((float4*)W2s)[t * 2]     = ((const float4*)W2)[t * 2];
    ((float4*)W2s)[t * 2 + 1] = ((const float4*)W2)[t * 2 + 1];
    if (t < D_H / 4) ((float4*)b1s)[t] = ((const float4*)b1)[t];
    if (t < N_EXP) b2s[t] = b2[t];
    __syncthreads();

    const int n0  = w * 64 + (lane & 31);   // C/D layout: col = lane&31
    const int n1  = n0 + 32;
    const float bn0 = b1s[n0];
    const float bn1 = b1s[n1];

    float* out_logits = out;
    float* out_w      = out + (size_t)N_TOK * N_EXP;
    float* out_i      = out_w + (size_t)N_TOK * 2;
    float* out_m      = out_i + (size_t)N_TOK * 2;

    auto reduce_rows = [&](int rt) {
#pragma unroll
        for (int rr2 = 0; rr2 < 4; ++rr2) {
            const int rl   = w * 4 + rr2;            // 8 waves x 4 = 32 rows
            const int grow = m0 + rt * 32 + rl;
            float4 ha = *(const float4*)&h_s[rl * 512 + lane * 4];
            float4 hb = *(const float4*)&h_s[rl * 512 + 256 + lane * 4];
            float v1 = -3.4e38f, v2 = -3.4e38f;
            int   i1 = 0, i2 = 0;
            float pls[8];
#pragma unroll
            for (int e = 0; e < N_EXP; ++e) {
                float4 wa = *(const float4*)&W2s[e * D_H + lane * 4];
                float4 wb = *(const float4*)&W2s[e * D_H + 256 + lane * 4];
                float s = ha.x * wa.x;
                s = fmaf(ha.y, wa.y, s);
                s = fmaf(ha.z, wa.z, s);
                s = fmaf(ha.w, wa.w, s);
                s = fmaf(hb.x, wb.x, s);
                s = fmaf(hb.y, wb.y, s);
                s = fmaf(hb.z, wb.z, s);
                s = fmaf(hb.w, wb.w, s);
#pragma unroll
                for (int off = 1; off < 64; off <<= 1)
                    s += __shfl_xor(s, off);
                s += b2s[e];
                pls[e] = s;
                if (s > v1)      { v2 = v1; i2 = i1; v1 = s; i1 = e; }
                else if (s > v2) { v2 = s;  i2 = e; }
            }
            const float rr   = expf(v2 - v1);
            const float wden = 1.f / (1.f + rr);
            if (lane == 0) {
                float4 lo4 = {pls[0], pls[1], pls[2], pls[3]};
                float4 hi4 = {pls[4], pls[5], pls[6], pls[7]};
                *(float4*)&out_logits[(size_t)grow * N_EXP]     = lo4;
                *(float4*)&out_logits[(size_t)grow * N_EXP + 4] = hi4;
                float2 wv = {wden, rr * wden};
                *(float2*)&out_w[(size_t)grow * 2] = wv;
                float2 iv = {(float)i1, (float)i2};
                *(float2*)&out_i[(size_t)grow * 2] = iv;
            }
            if (lane < 16) {
                const int e   = lane >> 1;
                const int kk  = lane & 1;
                const int sel = kk ? i2 : i1;
                out_m[((size_t)(e * 2 + kk)) * N_TOK + grow] = (sel == e) ? 1.0f : 0.0f;
            }
        }
    };

    // C/D row map (verified): in-tile row = (rr&3) + 8*(rr>>2) + 4*(lane>>5)
#define DO_GROUP(AC0, AC1, RT) do {                                            \
        _Pragma("unroll")                                                      \
        for (int rr = 0; rr < 16; ++rr) {                                      \
            const int rl = (rr & 3) + 8 * (rr >> 2) + 4 * (lane >> 5);         \
            h_s[rl * 512 + n0] = AC0[rr] + bn0;                                \
            h_s[rl * 512 + n1] = AC1[rr] + bn1;                                \
        }                                                                      \
        __syncthreads();                                                       \
        reduce_rows(RT);                                                       \
        __syncthreads();                                                       \
    } while (0)

    DO_GROUP(a0c0, a0c1, 0);
    DO_GROUP(a1c0, a1c1, 1);
    DO_GROUP(a2c0, a2c1, 2);
    DO_GROUP(a3c0, a3c1, 3);
#undef DO_GROUP
}

extern "C" void kernel_launch(void* const* d_in, const int* in_sizes, int n_in,
                              void* d_out, int out_size, void* d_ws, size_t ws_size,
                              hipStream_t stream) {
    const float* x  = (const float*)d_in[0];
    const float* W1 = (const float*)d_in[1];
    const float* b1 = (const float*)d_in[2];
    const float* W2 = (const float*)d_in[3];
    const float* b2 = (const float*)d_in[4];
    float* out = (float*)d_out;

    f16* wsH = (f16*)d_ws;                       // 1 MB
    f16* wsL = wsH + (size_t)WSLOTS * 8;         // 1 MB

    split_w1<<<WSLOTS / 256, 256, 0, stream>>>(W1, wsH, wsL);
    moe_router_mfma<<<N_TOK / BM, THREADS, 0, stream>>>(x, wsH, wsL, b1, W2, b2, out);
}

// Round 12
// 131.862 us; speedup vs baseline: 1.1439x; 1.0784x over previous
//
#include <hip/hip_runtime.h>
#include <math.h>

// MoE router on MFMA: logits = (x @ W1^T + b1) @ W2^T + b2; softmax; top-2; masks.
// N=32768, D=1024, D_H=512, E=8, K=2.
//
// Split-fp16: x = xh+xl, W1 = wh+wl; h = xh*wh + xl*wh + xh*wl (3 MFMA passes,
// fp32 acc). W1 pre-split/pre-packed into 32x32x16 fragment order in d_ws (r4).
//
// Round-12: r6 structure (best: 130.6us, no spill) + ONE change: the
// end-of-iteration __syncthreads() is replaced by the m201-verified raw
// barrier idiom {s_waitcnt lgkmcnt(0); s_barrier; sched_barrier(0)}.
// __syncthreads() makes the compiler emit s_waitcnt vmcnt(0) before
// s_barrier, draining the cross-iter B/x register prefetch every iteration
// (m233: this stage+vmcnt+barrier path is ~72% of 2-phase time; m218:
// counted-vs-drain = +38-73%). Register loads need no drain at a barrier;
// lgkmcnt(0) alone orders the A-tile ds_writes/ds_reads.

#define N_TOK 32768
#define D_IN  1024
#define D_H   512
#define N_EXP 8

#define BM      128
#define BK      16
#define THREADS 512
#define NKT     (D_IN / BK)   // 64 k-tiles
#define WSLOTS  (NKT * 1024)  // W1 frag slots per hi/lo plane

typedef _Float16 f16;
typedef __attribute__((ext_vector_type(4)))  _Float16 f16x4;
typedef __attribute__((ext_vector_type(8)))  _Float16 f16x8;
typedef __attribute__((ext_vector_type(16))) float    f32x16;

#define MFMA(a, b, c) __builtin_amdgcn_mfma_f32_32x32x16_f16((a), (b), (c), 0, 0, 0)

// raw k-loop barrier: LDS-order only, NO vmcnt drain (keeps B/x prefetch alive)
#define KBAR() do {                                                            \
        asm volatile("s_waitcnt lgkmcnt(0)" ::: "memory");                     \
        __builtin_amdgcn_s_barrier();                                          \
        __builtin_amdgcn_sched_barrier(0);                                     \
    } while (0)

// ---- pre-kernel: split W1 into hi/lo f16 fragments in ws (verified r4-r11) ----
__global__ void split_w1(const float* __restrict__ W1,
                         f16* __restrict__ wsH, f16* __restrict__ wsL) {
    const int s = blockIdx.x * 256 + threadIdx.x;   // 0..65535
    const int kt  = s >> 10;
    const int ctg = (s >> 6) & 15;
    const int l   = s & 63;
    const int n   = ctg * 32 + (l & 31);
    const int k   = kt * BK + (l >> 5) * 8;
    const float* src = &W1[(size_t)n * D_IN + k];
    float4 a0 = *(const float4*)src;
    float4 a1 = *(const float4*)(src + 4);
    f16x8 hi, lo;
#pragma unroll
    for (int j = 0; j < 4; ++j) {
        float v0 = ((const float*)&a0)[j];
        float v1 = ((const float*)&a1)[j];
        _Float16 h0 = (_Float16)v0, h1 = (_Float16)v1;
        hi[j] = h0;     hi[j + 4] = h1;
        lo[j] = (_Float16)(v0 - (float)h0);
        lo[j + 4] = (_Float16)(v1 - (float)h1);
    }
    *(f16x8*)&wsH[(size_t)s * 8] = hi;
    *(f16x8*)&wsL[(size_t)s * 8] = lo;
}

// ---- main kernel ----
__global__ __launch_bounds__(THREADS, 1)   // 1 block/CU -> 2 waves/SIMD -> 256 unified regs
void moe_router_mfma(const float* __restrict__ x,
                     const f16* __restrict__ wH,
                     const f16* __restrict__ wL,
                     const float* __restrict__ b1,
                     const float* __restrict__ W2,
                     const float* __restrict__ b2,
                     float* __restrict__ out)
{
    __shared__ __align__(16) f16   AS[2 * 2 * 2048];     // A frags dbuf: 16 KB
    __shared__ __align__(16) float h_s[32 * 512];        // epilogue h: 64 KB
    __shared__ __align__(16) float W2s[N_EXP * D_H];     // 16 KB
    __shared__ __align__(16) float b1s[D_H];             // 2 KB
    __shared__ float b2s[N_EXP];

    const int t    = threadIdx.x;
    const int w    = t >> 6;
    const int lane = t & 63;
    const int m0   = blockIdx.x * BM;

    // 8 accumulators: row-tile rt=0..3 x col c=0..1 (wave owns cols 2w,2w+1)
    f32x16 a0c0 = {}, a0c1 = {}, a1c0 = {}, a1c1 = {};
    f32x16 a2c0 = {}, a2c1 = {}, a3c0 = {}, a3c1 = {};

    // A staging geometry (verified r4-r11): thread t -> frag fA=t>>1, qA=t&1.
    const int fA   = t >> 1;
    const int qA   = t & 1;
    const int rowA = (fA >> 6) * 32 + (fA & 31);
    const int kA   = ((fA >> 5) & 1) * 8 + qA * 4;
    const float* xsrc = x + (size_t)(m0 + rowA) * D_IN + kA;
    const int aDst = fA * 8 + qA * 4;

    // B frag offsets for this wave (f16 elems within one ktile plane)
    const size_t bOff0 = (size_t)(2 * w + 0) * 512 + (size_t)lane * 8;
    const size_t bOff1 = (size_t)(2 * w + 1) * 512 + (size_t)lane * 8;

    auto stageAwrite = [&](const float4& xv, int buf) {
        f16x4 hi, lo;
        float v[4] = {xv.x, xv.y, xv.z, xv.w};
#pragma unroll
        for (int j = 0; j < 4; ++j) {
            _Float16 h = (_Float16)v[j];
            hi[j] = h;
            lo[j] = (_Float16)(v[j] - (float)h);
        }
        *(f16x4*)&AS[(buf * 2 + 0) * 2048 + aDst] = hi;
        *(f16x4*)&AS[(buf * 2 + 1) * 2048 + aDst] = lo;
    };

    // ---- prologue: B regs + A LDS for ktile 0 ----
    f16x8 Bh0A = *(const f16x8*)(wH + bOff0);
    f16x8 Bh1A = *(const f16x8*)(wH + bOff1);
    f16x8 Bl0A = *(const f16x8*)(wL + bOff0);
    f16x8 Bl1A = *(const f16x8*)(wL + bOff1);
    f16x8 Bh0B, Bh1B, Bl0B, Bl1B;
    {
        float4 xv = *(const float4*)xsrc;
        stageAwrite(xv, 0);
    }
    __syncthreads();

    // One ktile body. BUF = A-buffer of this ktile; B cur regs named in;
    // B next regs named out (loaded here, consumed next body).
#define BODY(BUF, KT, BH0, BH1, BL0, BL1, NH0, NH1, NL0, NL1) do {             \
        float4 xnxt = {0.f, 0.f, 0.f, 0.f};                                    \
        if ((KT) + 1 < NKT) {                                                  \
            const size_t nb = (size_t)((KT) + 1) * 8192;                       \
            NH0 = *(const f16x8*)(wH + nb + bOff0);                            \
            NH1 = *(const f16x8*)(wH + nb + bOff1);                            \
            NL0 = *(const f16x8*)(wL + nb + bOff0);                            \
            NL1 = *(const f16x8*)(wL + nb + bOff1);                            \
            xnxt = *(const float4*)(xsrc + (size_t)((KT) + 1) * BK);           \
        }                                                                      \
        const f16* ah = &AS[((BUF) * 2 + 0) * 2048];                           \
        const f16* al = &AS[((BUF) * 2 + 1) * 2048];                           \
        f16x8 ah0 = *(const f16x8*)&ah[(0 * 64 + lane) * 8];                   \
        f16x8 al0 = *(const f16x8*)&al[(0 * 64 + lane) * 8];                   \
        f16x8 ah1 = *(const f16x8*)&ah[(1 * 64 + lane) * 8];                   \
        f16x8 al1 = *(const f16x8*)&al[(1 * 64 + lane) * 8];                   \
        f16x8 ah2 = *(const f16x8*)&ah[(2 * 64 + lane) * 8];                   \
        f16x8 al2 = *(const f16x8*)&al[(2 * 64 + lane) * 8];                   \
        f16x8 ah3 = *(const f16x8*)&ah[(3 * 64 + lane) * 8];                   \
        f16x8 al3 = *(const f16x8*)&al[(3 * 64 + lane) * 8];                   \
        __builtin_amdgcn_s_setprio(1);                                         \
        a0c0 = MFMA(ah0, BH0, a0c0); a0c0 = MFMA(al0, BH0, a0c0);              \
        a0c0 = MFMA(ah0, BL0, a0c0);                                           \
        a1c0 = MFMA(ah1, BH0, a1c0); a1c0 = MFMA(al1, BH0, a1c0);              \
        a1c0 = MFMA(ah1, BL0, a1c0);                                           \
        a2c0 = MFMA(ah2, BH0, a2c0); a2c0 = MFMA(al2, BH0, a2c0);              \
        a2c0 = MFMA(ah2, BL0, a2c0);                                           \
        a3c0 = MFMA(ah3, BH0, a3c0); a3c0 = MFMA(al3, BH0, a3c0);              \
        a3c0 = MFMA(ah3, BL0, a3c0);                                           \
        __builtin_amdgcn_s_setprio(0);                                         \
        __builtin_amdgcn_s_barrier();                                          \
        __builtin_amdgcn_s_setprio(1);                                         \
        a0c1 = MFMA(ah0, BH1, a0c1); a0c1 = MFMA(al0, BH1, a0c1);              \
        a0c1 = MFMA(ah0, BL1, a0c1);                                           \
        a1c1 = MFMA(ah1, BH1, a1c1); a1c1 = MFMA(al1, BH1, a1c1);              \
        a1c1 = MFMA(ah1, BL1, a1c1);                                           \
        a2c1 = MFMA(ah2, BH1, a2c1); a2c1 = MFMA(al2, BH1, a2c1);              \
        a2c1 = MFMA(ah2, BL1, a2c1);                                           \
        a3c1 = MFMA(ah3, BH1, a3c1); a3c1 = MFMA(al3, BH1, a3c1);              \
        a3c1 = MFMA(ah3, BL1, a3c1);                                           \
        __builtin_amdgcn_s_setprio(0);                                         \
        if ((KT) + 1 < NKT) stageAwrite(xnxt, (BUF) ^ 1);                      \
        KBAR();   /* lgkm-only barrier: B/x prefetch stays in flight */        \
    } while (0)

    for (int kt = 0; kt < NKT; kt += 2) {
        BODY(0, kt,     Bh0A, Bh1A, Bl0A, Bl1A, Bh0B, Bh1B, Bl0B, Bl1B);
        BODY(1, kt + 1, Bh0B, Bh1B, Bl0B, Bl1B, Bh0A, Bh1A, Bl0A, Bl1A);
    }
#undef BODY

    // ---- epilogue (router tail verified r4-r11) ----
    ((float4*)W2s)[t * 2]     = ((const float4*)W2)[t * 2];
    ((float4*)W2s)[t * 2 + 1] = ((const float4*)W2)[t * 2 + 1];
    if (t < D_H / 4) ((float4*)b1s)[t] = ((const float4*)b1)[t];
    if (t < N_EXP) b2s[t] = b2[t];
    __syncthreads();

    const int n0  = w * 64 + (lane & 31);   // C/D layout: col = lane&31
    const int n1  = n0 + 32;
    const float bn0 = b1s[n0];
    const float bn1 = b1s[n1];

    float* out_logits = out;
    float* out_w      = out + (size_t)N_TOK * N_EXP;
    float* out_i      = out_w + (size_t)N_TOK * 2;
    float* out_m      = out_i + (size_t)N_TOK * 2;

    auto reduce_rows = [&](int rt) {
#pragma unroll
        for (int rr2 = 0; rr2 < 4; ++rr2) {
            const int rl   = w * 4 + rr2;            // 8 waves x 4 = 32 rows
            const int grow = m0 + rt * 32 + rl;
            float4 ha = *(const float4*)&h_s[rl * 512 + lane * 4];
            float4 hb = *(const float4*)&h_s[rl * 512 + 256 + lane * 4];
            float v1 = -3.4e38f, v2 = -3.4e38f;
            int   i1 = 0, i2 = 0;
            float pls[8];
#pragma unroll
            for (int e = 0; e < N_EXP; ++e) {
                float4 wa = *(const float4*)&W2s[e * D_H + lane * 4];
                float4 wb = *(const float4*)&W2s[e * D_H + 256 + lane * 4];
                float s = ha.x * wa.x;
                s = fmaf(ha.y, wa.y, s);
                s = fmaf(ha.z, wa.z, s);
                s = fmaf(ha.w, wa.w, s);
                s = fmaf(hb.x, wb.x, s);
                s = fmaf(hb.y, wb.y, s);
                s = fmaf(hb.z, wb.z, s);
                s = fmaf(hb.w, wb.w, s);
#pragma unroll
                for (int off = 1; off < 64; off <<= 1)
                    s += __shfl_xor(s, off);
                s += b2s[e];
                pls[e] = s;
                if (s > v1)      { v2 = v1; i2 = i1; v1 = s; i1 = e; }
                else if (s > v2) { v2 = s;  i2 = e; }
            }
            const float rr   = expf(v2 - v1);
            const float wden = 1.f / (1.f + rr);
            if (lane == 0) {
                float4 lo4 = {pls[0], pls[1], pls[2], pls[3]};
                float4 hi4 = {pls[4], pls[5], pls[6], pls[7]};
                *(float4*)&out_logits[(size_t)grow * N_EXP]     = lo4;
                *(float4*)&out_logits[(size_t)grow * N_EXP + 4] = hi4;
                float2 wv = {wden, rr * wden};
                *(float2*)&out_w[(size_t)grow * 2] = wv;
                float2 iv = {(float)i1, (float)i2};
                *(float2*)&out_i[(size_t)grow * 2] = iv;
            }
            if (lane < 16) {
                const int e   = lane >> 1;
                const int kk  = lane & 1;
                const int sel = kk ? i2 : i1;
                out_m[((size_t)(e * 2 + kk)) * N_TOK + grow] = (sel == e) ? 1.0f : 0.0f;
            }
        }
    };

    // C/D row map (verified): in-tile row = (rr&3) + 8*(rr>>2) + 4*(lane>>5)
#define DO_GROUP(AC0, AC1, RT) do {                                            \
        _Pragma("unroll")                                                      \
        for (int rr = 0; rr < 16; ++rr) {                                      \
            const int rl = (rr & 3) + 8 * (rr >> 2) + 4 * (lane >> 5);         \
            h_s[rl * 512 + n0] = AC0[rr] + bn0;                                \
            h_s[rl * 512 + n1] = AC1[rr] + bn1;                                \
        }                                                                      \
        __syncthreads();                                                       \
        reduce_rows(RT);                                                       \
        __syncthreads();                                                       \
    } while (0)

    DO_GROUP(a0c0, a0c1, 0);
    DO_GROUP(a1c0, a1c1, 1);
    DO_GROUP(a2c0, a2c1, 2);
    DO_GROUP(a3c0, a3c1, 3);
#undef DO_GROUP
}

extern "C" void kernel_launch(void* const* d_in, const int* in_sizes, int n_in,
                              void* d_out, int out_size, void* d_ws, size_t ws_size,
                              hipStream_t stream) {
    const float* x  = (const float*)d_in[0];
    const float* W1 = (const float*)d_in[1];
    const float* b1 = (const float*)d_in[2];
    const float* W2 = (const float*)d_in[3];
    const float* b2 = (const float*)d_in[4];
    float* out = (float*)d_out;

    f16* wsH = (f16*)d_ws;                       // 1 MB
    f16* wsL = wsH + (size_t)WSLOTS * 8;         // 1 MB

    split_w1<<<WSLOTS / 256, 256, 0, stream>>>(W1, wsH, wsL);
    moe_router_mfma<<<N_TOK / BM, THREADS, 0, stream>>>(x, wsH, wsL, b1, W2, b2, out);
}